// Round 12
// baseline (1239.759 us; speedup 1.0000x reference)
//
#include <hip/hip_runtime.h>
#include <stdint.h>

#define NN 50000
#define NE 800000
#define HID 128
#define NG 500
#define NL 7

typedef short bf16x8 __attribute__((ext_vector_type(8)));
typedef float f32x4 __attribute__((ext_vector_type(4)));

__device__ __forceinline__ unsigned short f2bf(float f) {
  unsigned int u = __builtin_bit_cast(unsigned int, f);
  u += 0x7FFFu + ((u >> 16) & 1u);
  return (unsigned short)(u >> 16);
}
__device__ __forceinline__ float bf2f(unsigned short h) {
  unsigned int u = ((unsigned int)h) << 16;
  return __builtin_bit_cast(float, u);
}
__device__ __forceinline__ float bflo(unsigned int u) {
  return __builtin_bit_cast(float, u << 16);
}
__device__ __forceinline__ float bfhi(unsigned int u) {
  return __builtin_bit_cast(float, u & 0xffff0000u);
}

// ---- fused preprocessing: cvt + pad rows + degree histogram + weight swizzle ----
__global__ void k_pre(const float* __restrict__ x, unsigned short* __restrict__ hA,
                      unsigned short* __restrict__ hB,
                      const int* __restrict__ dstE, int* __restrict__ deg,
                      const float* __restrict__ Wl, const float* __restrict__ Wr,
                      unsigned short* __restrict__ wswh,
                      unsigned short* __restrict__ wswl) {
  int i = blockIdx.x * 256 + threadIdx.x;
  if (i < NN * HID / 4) {
    float4 v = ((const float4*)x)[i];
    ushort4 r;
    r.x = f2bf(v.x); r.y = f2bf(v.y); r.z = f2bf(v.z); r.w = f2bf(v.w);
    ((ushort4*)hA)[i] = r;
  }
  if (i < NE) atomicAdd(&deg[dstE[i]], 1);
  if (i < NL * 2 * 4 * 4096) {
    int j = i & 7, ii = (i >> 3) & 15, q = (i >> 7) & 3, t = (i >> 9) & 7;
    int cc = (i >> 12) & 3, m = (i >> 14) & 1, l = i >> 15;
    int k = cc * 32 + q * 8 + j, n = t * 16 + ii;
    const float* W = m ? Wr : Wl;
    float w = W[l * HID * HID + k * HID + n];
    unsigned short hi = f2bf(w);
    unsigned short lo = f2bf(w - bf2f(hi));
    wswh[i] = hi;
    wswl[i] = lo;
  }
  if (i < 2048) {  // zero 64 pad rows of each h buffer (rows NN..NN+63)
    int b = i >> 10, r = (i >> 4) & 63, u = i & 15;
    unsigned short* pad = (b ? hB : hA) + (size_t)(NN + r) * HID;
    *(uint4*)&pad[u * 8] = make_uint4(0u, 0u, 0u, 0u);
  }
}

// ---- exclusive scan (3 kernels) ----
__global__ void k_scan1(const int* __restrict__ deg, int* __restrict__ offs,
                        int* __restrict__ bsum) {
  int i = blockIdx.x * 256 + threadIdx.x;
  int v = (i < NN) ? deg[i] : 0;
  int lane = threadIdx.x & 63, wv = threadIdx.x >> 6;
  int x = v;
  #pragma unroll
  for (int d = 1; d < 64; d <<= 1) {
    int y = __shfl_up(x, d, 64);
    if (lane >= d) x += y;
  }
  __shared__ int wsum[4];
  if (lane == 63) wsum[wv] = x;
  __syncthreads();
  if (threadIdx.x == 0) {
    int s = 0;
    for (int k = 0; k < 4; k++) { int t = wsum[k]; wsum[k] = s; s += t; }
    bsum[blockIdx.x] = s;
  }
  __syncthreads();
  if (i < NN) offs[i] = x - v + wsum[wv];
}

__global__ void k_scan2(int* __restrict__ bsum, int nb) {
  int i = threadIdx.x;
  int v = (i < nb) ? bsum[i] : 0;
  int lane = threadIdx.x & 63, wv = threadIdx.x >> 6;
  int x = v;
  #pragma unroll
  for (int d = 1; d < 64; d <<= 1) {
    int y = __shfl_up(x, d, 64);
    if (lane >= d) x += y;
  }
  __shared__ int wsum[4];
  if (lane == 63) wsum[wv] = x;
  __syncthreads();
  if (threadIdx.x == 0) {
    int s = 0;
    for (int k = 0; k < 4; k++) { int t = wsum[k]; wsum[k] = s; s += t; }
  }
  __syncthreads();
  if (i < nb) bsum[i] = x - v + wsum[wv];
}

__global__ void k_scan3(const int* __restrict__ deg, int* __restrict__ offs,
                        const int* __restrict__ bsum, float* __restrict__ invd) {
  int i = blockIdx.x * 256 + threadIdx.x;
  if (i < NN) {
    offs[i] += bsum[blockIdx.x];
    int d = deg[i];
    invd[i] = 1.0f / (float)(d > 0 ? d : 1);
    if (i == 0) offs[NN] = NE;
  }
}

// ---- CSR fill: dst-range partitioned, XCD-affine (blockIdx%8 -> XCD round robin).
#define FILL_CHUNK (NE / 128)   // 6250
__global__ void k_fill(const int* __restrict__ src, const int* __restrict__ dst,
                       const int* __restrict__ offs, int* __restrict__ cur,
                       int* __restrict__ csr) {
  const int r = blockIdx.x & 7;          // intended XCD
  const int chunk = blockIdx.x >> 3;     // 0..127
  const int lo = r * (NN / 8), hi = lo + (NN / 8);
  const int e0 = chunk * FILL_CHUNK;
  for (int e = e0 + threadIdx.x; e < e0 + FILL_CHUNK; e += 256) {
    int d = dst[e];
    if (d >= lo && d < hi) {
      int p = atomicAdd(&cur[d], 1);
      csr[offs[d] + p] = src[e];
    }
  }
}

// ---- degree-bucket sort: bucket = ceil(deg/8) = gather iteration count.
// Nodes processed in bucket order -> the 8 nodes sharing a wave have equal
// trip counts (kills the E[max of 8] ~ 1.27x idle-lane tax).
__global__ void k_b1(const int* __restrict__ deg, int* __restrict__ bcnt) {
  int i = blockIdx.x * 256 + threadIdx.x;
  if (i < NN) {
    int b = (deg[i] + 7) >> 3; if (b > 15) b = 15;
    atomicAdd(&bcnt[b], 1);
  }
}
__global__ void k_bscan(const int* __restrict__ bcnt, int* __restrict__ boff) {
  if (threadIdx.x == 0) {
    int s = 0;
    for (int k = 0; k < 16; k++) { boff[k] = s; s += bcnt[k]; }
  }
}
__global__ void k_b2(const int* __restrict__ deg, int* __restrict__ boff,
                     int* __restrict__ perm) {
  int i = blockIdx.x * 256 + threadIdx.x;
  if (i < NN) {
    int b = (deg[i] + 7) >> 3; if (b > 15) b = 15;
    int p = atomicAdd(&boff[b], 1);
    perm[p] = i;
  }
}

#define ACC8(V) { a0 += bflo(V.x); a1 += bfhi(V.x); a2 += bflo(V.y); \
                  a3 += bfhi(V.y); a4 += bflo(V.z); a5 += bfhi(V.z); \
                  a6 += bflo(V.w); a7 += bfhi(V.w); }

#define LOADSTRIP(P0,P1,P2,P3,P4,P5,P6,P7,IDX) \
  P0 = *(const uint4*)(rowbase + (size_t)__shfl(IDX, 0, 8) * HID); \
  P1 = *(const uint4*)(rowbase + (size_t)__shfl(IDX, 1, 8) * HID); \
  P2 = *(const uint4*)(rowbase + (size_t)__shfl(IDX, 2, 8) * HID); \
  P3 = *(const uint4*)(rowbase + (size_t)__shfl(IDX, 3, 8) * HID); \
  P4 = *(const uint4*)(rowbase + (size_t)__shfl(IDX, 4, 8) * HID); \
  P5 = *(const uint4*)(rowbase + (size_t)__shfl(IDX, 5, 8) * HID); \
  P6 = *(const uint4*)(rowbase + (size_t)__shfl(IDX, 6, 8) * HID); \
  P7 = *(const uint4*)(rowbase + (size_t)__shfl(IDX, 7, 8) * HID);

// ---- gather: round-11 pipelined strip (proven +13us) + degree-sorted node
// order via perm[]: pos = consecutive perm position -> wave's 8 nodes come
// from the same degree bucket -> equal trip counts. slice = blockIdx&1 keeps
// the column-half split; q-quarter XCD mapping dropped (sorted quarters would
// skew per-XCD work).
__global__ __launch_bounds__(256, 6) void k_agg(const unsigned short* __restrict__ curh,
                                                const int* __restrict__ offs,
                                                const int* __restrict__ csr,
                                                const float* __restrict__ invd,
                                                const int* __restrict__ perm,
                                                unsigned short* __restrict__ agg) {
  const int slice = blockIdx.x & 1;    // column band
  const int tid = threadIdx.x;
  const int grp = tid >> 3, l = tid & 7;
  const int pos = (blockIdx.x >> 1) * 32 + grp;
  if (pos >= NN) return;
  const int node = perm[pos];
  const unsigned short* rowbase = curh + slice * 64 + l * 8;
  float a0 = 0.f, a1 = 0.f, a2 = 0.f, a3 = 0.f;
  float a4 = 0.f, a5 = 0.f, a6 = 0.f, a7 = 0.f;
  const int s = offs[node], e = offs[node + 1];
  if (s < e) {
    uint4 p0, p1, p2, p3, p4, p5, p6, p7;
    int idx = (s + l < e) ? csr[s + l] : NN;   // pad row NN = zeros
    LOADSTRIP(p0, p1, p2, p3, p4, p5, p6, p7, idx)
    for (int base = s + 8; base < e; base += 8) {
      uint4 n0, n1, n2, n3, n4, n5, n6, n7;
      int idx2 = (base + l < e) ? csr[base + l] : NN;
      LOADSTRIP(n0, n1, n2, n3, n4, n5, n6, n7, idx2)   // in flight during ACC
      ACC8(p0) ACC8(p1) ACC8(p2) ACC8(p3)
      ACC8(p4) ACC8(p5) ACC8(p6) ACC8(p7)
      p0 = n0; p1 = n1; p2 = n2; p3 = n3;
      p4 = n4; p5 = n5; p6 = n6; p7 = n7;
    }
    ACC8(p0) ACC8(p1) ACC8(p2) ACC8(p3)
    ACC8(p4) ACC8(p5) ACC8(p6) ACC8(p7)
  }
  float sc = invd[node];
  a0 *= sc; a1 *= sc; a2 *= sc; a3 *= sc;
  a4 *= sc; a5 *= sc; a6 *= sc; a7 *= sc;
  unsigned int w0 = (unsigned int)f2bf(a0) | ((unsigned int)f2bf(a1) << 16);
  unsigned int w1 = (unsigned int)f2bf(a2) | ((unsigned int)f2bf(a3) << 16);
  unsigned int w2 = (unsigned int)f2bf(a4) | ((unsigned int)f2bf(a5) << 16);
  unsigned int w3 = (unsigned int)f2bf(a6) | ((unsigned int)f2bf(a7) << 16);
  *(uint4*)(agg + (size_t)node * HID + slice * 64 + l * 8) =
      make_uint4(w0, w1, w2, w3);
}

// ---- GEMM: out = relu?( agg@Wl + bl + h@Wr ); double-buffered weight staging.
// Chunk c+1's global loads issue BEFORE chunk c's MFMAs, land in the other
// LDS buffer after; one barrier per iteration (9 vs 16) and staging latency
// hides under compute. (Barrier-free-from-global variant regressed in r7:
// ~400MB/layer L2 re-reads; this keeps the LDS sharing.)
__global__ __launch_bounds__(256) void k_gemm(const unsigned short* __restrict__ agg,
                                              const unsigned short* __restrict__ curh,
                                              const unsigned short* __restrict__ wswh,
                                              const unsigned short* __restrict__ wswl,
                                              const float* __restrict__ bias,
                                              unsigned short* __restrict__ out,
                                              int relu) {
  __shared__ __align__(16) unsigned short sW2[2][8192];  // double-buffered Whi|Wlo
  const int tid = threadIdx.x;
  const int lane = tid & 63, wv = tid >> 6;
  const int row0 = blockIdx.x * 64;
  const int mr = (wv << 4) + (lane & 15);
  const int q = lane >> 4;
  const unsigned short* aRow = agg + (size_t)(row0 + mr) * HID + q * 8;
  const unsigned short* hRow = curh + (size_t)(row0 + mr) * HID + q * 8;

  f32x4 acc[8];
  #pragma unroll
  for (int t = 0; t < 8; t++) acc[t] = (f32x4){0.f, 0.f, 0.f, 0.f};

  {
    const uint4* wh = (const uint4*)wswh;
    const uint4* wl = (const uint4*)wswl;
    ((uint4*)sW2[0])[tid] = wh[tid];
    ((uint4*)sW2[0])[tid + 256] = wh[tid + 256];
    ((uint4*)sW2[0])[tid + 512] = wl[tid];
    ((uint4*)sW2[0])[tid + 768] = wl[tid + 256];
  }
  __syncthreads();

  for (int c = 0; c < 8; ++c) {
    uint4 u0, u1, u2, u3;
    if (c < 7) {
      const uint4* wh = (const uint4*)(wswh + (c + 1) * 4096);
      const uint4* wl = (const uint4*)(wswl + (c + 1) * 4096);
      u0 = wh[tid]; u1 = wh[tid + 256]; u2 = wl[tid]; u3 = wl[tid + 256];
    }
    const unsigned short* buf = sW2[c & 1];
    bf16x8 a = *(const bf16x8*)(((c < 4) ? aRow : hRow) + (c & 3) * 32);
    #pragma unroll
    for (int t = 0; t < 8; t++) {
      bf16x8 bh = *(const bf16x8*)&buf[(t * 4 + q) * 128 + (lane & 15) * 8];
      bf16x8 bl2 = *(const bf16x8*)&buf[4096 + (t * 4 + q) * 128 + (lane & 15) * 8];
      acc[t] = __builtin_amdgcn_mfma_f32_16x16x32_bf16(a, bh, acc[t], 0, 0, 0);
      acc[t] = __builtin_amdgcn_mfma_f32_16x16x32_bf16(a, bl2, acc[t], 0, 0, 0);
    }
    if (c < 7) {
      unsigned short* nb = sW2[(c + 1) & 1];
      ((uint4*)nb)[tid] = u0;
      ((uint4*)nb)[tid + 256] = u1;
      ((uint4*)nb)[tid + 512] = u2;
      ((uint4*)nb)[tid + 768] = u3;
    }
    __syncthreads();
  }

  const int ci = lane & 15;
  const int rb = (wv << 4) + (lane >> 4) * 4;
  #pragma unroll
  for (int t = 0; t < 8; t++) {
    int n = t * 16 + ci;
    float bn = bias[n];
    #pragma unroll
    for (int r2 = 0; r2 < 4; r2++) {
      int row = row0 + rb + r2;
      if (row < NN) {
        float v = acc[t][r2] + bn;
        if (relu) v = fmaxf(v, 0.f);
        out[(size_t)row * HID + n] = f2bf(v);
      }
    }
  }
}

// ---- global add pool (batch sorted -> binary search; 2-row MLP) ----
__global__ void k_pool(const unsigned short* __restrict__ h,
                       const int* __restrict__ batch, float* __restrict__ pooled) {
  int g = blockIdx.x;
  __shared__ int rng[2];
  __shared__ float tmp[HID];
  if (threadIdx.x < 2) {
    int target = g + threadIdx.x;
    int lo = 0, hi = NN;
    while (lo < hi) {
      int mid = (lo + hi) >> 1;
      if (batch[mid] < target) lo = mid + 1; else hi = mid;
    }
    rng[threadIdx.x] = lo;
  }
  __syncthreads();
  int s = rng[0], e = rng[1];
  int f = threadIdx.x & 127, ro = threadIdx.x >> 7;  // 256 threads: 2 row streams
  float a = 0.f;
  for (int r = s + ro; r < e; r += 2) a += bf2f(h[(size_t)r * HID + f]);
  if (ro == 1) tmp[f] = a;
  __syncthreads();
  if (ro == 0) pooled[g * HID + f] = a + tmp[f];
}

// ---- final projection 128 -> 2 (all fp32) ----
__global__ void k_out(const float* __restrict__ pooled,
                      const float* __restrict__ Wout,
                      const float* __restrict__ bout,
                      float* __restrict__ out) {
  int g = blockIdx.x;
  int l = threadIdx.x;  // 64
  float a = pooled[g * HID + l], b = pooled[g * HID + 64 + l];
  float p0 = a * Wout[l * 2] + b * Wout[(l + 64) * 2];
  float p1 = a * Wout[l * 2 + 1] + b * Wout[(l + 64) * 2 + 1];
  #pragma unroll
  for (int d = 32; d; d >>= 1) {
    p0 += __shfl_down(p0, d, 64);
    p1 += __shfl_down(p1, d, 64);
  }
  if (l == 0) {
    out[g * 2] = p0 + bout[0];
    out[g * 2 + 1] = p1 + bout[1];
  }
}

extern "C" void kernel_launch(void* const* d_in, const int* in_sizes, int n_in,
                              void* d_out, int out_size, void* d_ws, size_t ws_size,
                              hipStream_t stream) {
  const float* x = (const float*)d_in[0];
  const int* ei = (const int*)d_in[1];
  const int* batch = (const int*)d_in[2];
  const float* Wl = (const float*)d_in[3];
  const float* Wr = (const float*)d_in[4];
  const float* bl = (const float*)d_in[5];
  const float* Wout = (const float*)d_in[6];
  const float* bout = (const float*)d_in[7];
  float* out = (float*)d_out;
  const int* srcE = ei;
  const int* dstE = ei + NE;

  // workspace layout (~43 MB); h buffers padded to NN+64 rows (zeroed)
  char* w = (char*)d_ws;
  unsigned short* hA = (unsigned short*)w;  w += (size_t)(NN + 64) * HID * 2;
  unsigned short* hB = (unsigned short*)w;  w += (size_t)(NN + 64) * HID * 2;
  unsigned short* agg = (unsigned short*)w; w += (size_t)(NN + 64) * HID * 2;
  float* invd = (float*)w;   w += (size_t)NN * 4;
  float* pooled = (float*)w; w += (size_t)NG * HID * 4;
  int* deg = (int*)w;  w += (size_t)NN * 4;
  int* cur = (int*)w;  w += (size_t)NN * 4;      // adjacent to deg
  int* bcnt = (int*)w; w += 16 * 4;              // adjacent: covered by memset
  int* boff = (int*)w; w += 16 * 4;
  int* perm = (int*)w; w += (size_t)NN * 4;
  int* offs = (int*)w; w += (size_t)50004 * 4;
  int* csr = (int*)w;  w += (size_t)NE * 4;
  int* bsum = (int*)w; w += 256 * 4;
  unsigned short* wswh = (unsigned short*)w; w += (size_t)NL * 2 * 4 * 4096 * 2;
  unsigned short* wswl = (unsigned short*)w;

  hipMemsetAsync(deg, 0, ((size_t)NN * 2 + 16) * 4, stream);  // deg+cur+bcnt
  k_pre<<<(NN * HID / 4 + 255) / 256, 256, 0, stream>>>(x, hA, hB, dstE, deg,
                                                        Wl, Wr, wswh, wswl);
  int nb = (NN + 255) / 256;
  k_scan1<<<nb, 256, 0, stream>>>(deg, offs, bsum);
  k_scan2<<<1, 256, 0, stream>>>(bsum, nb);
  k_scan3<<<nb, 256, 0, stream>>>(deg, offs, bsum, invd);
  k_fill<<<1024, 256, 0, stream>>>(srcE, dstE, offs, cur, csr);
  k_b1<<<nb, 256, 0, stream>>>(deg, bcnt);
  k_bscan<<<1, 64, 0, stream>>>(bcnt, boff);
  k_b2<<<nb, 256, 0, stream>>>(deg, boff, perm);

  unsigned short* curh = hA;
  unsigned short* nxth = hB;
  const int aggGrid = ((NN + 31) / 32) * 2;  // 1563*2 = 3126
  for (int l = 0; l < NL; l++) {
    k_agg<<<aggGrid, 256, 0, stream>>>(curh, offs, csr, invd, perm, agg);
    k_gemm<<<(NN + 63) / 64, 256, 0, stream>>>(agg, curh,
                                               wswh + (size_t)l * 2 * 4 * 4096,
                                               wswl + (size_t)l * 2 * 4 * 4096,
                                               bl + l * HID, nxth,
                                               (l < NL - 1) ? 1 : 0);
    unsigned short* t = curh; curh = nxth; nxth = t;
  }
  k_pool<<<NG, 256, 0, stream>>>(curh, batch, pooled);
  k_out<<<NG, 64, 0, stream>>>(pooled, Wout, bout, out);
}

// Round 13
// 511.135 us; speedup vs baseline: 2.4255x; 2.4255x over previous
//
#include <hip/hip_runtime.h>
#include <stdint.h>

#define NN 50000
#define NE 800000
#define HID 128
#define NG 500
#define NL 7

typedef short bf16x8 __attribute__((ext_vector_type(8)));
typedef float f32x4 __attribute__((ext_vector_type(4)));

__device__ __forceinline__ unsigned short f2bf(float f) {
  unsigned int u = __builtin_bit_cast(unsigned int, f);
  u += 0x7FFFu + ((u >> 16) & 1u);
  return (unsigned short)(u >> 16);
}
__device__ __forceinline__ float bf2f(unsigned short h) {
  unsigned int u = ((unsigned int)h) << 16;
  return __builtin_bit_cast(float, u);
}
__device__ __forceinline__ float bflo(unsigned int u) {
  return __builtin_bit_cast(float, u << 16);
}
__device__ __forceinline__ float bfhi(unsigned int u) {
  return __builtin_bit_cast(float, u & 0xffff0000u);
}

// ---- fused preprocessing: cvt + pad rows + degree histogram + weight swizzle ----
__global__ void k_pre(const float* __restrict__ x, unsigned short* __restrict__ hA,
                      unsigned short* __restrict__ hB,
                      const int* __restrict__ dstE, int* __restrict__ deg,
                      const float* __restrict__ Wl, const float* __restrict__ Wr,
                      unsigned short* __restrict__ wswh,
                      unsigned short* __restrict__ wswl) {
  int i = blockIdx.x * 256 + threadIdx.x;
  if (i < NN * HID / 4) {
    float4 v = ((const float4*)x)[i];
    ushort4 r;
    r.x = f2bf(v.x); r.y = f2bf(v.y); r.z = f2bf(v.z); r.w = f2bf(v.w);
    ((ushort4*)hA)[i] = r;
  }
  if (i < NE) atomicAdd(&deg[dstE[i]], 1);
  if (i < NL * 2 * 4 * 4096) {
    int j = i & 7, ii = (i >> 3) & 15, q = (i >> 7) & 3, t = (i >> 9) & 7;
    int cc = (i >> 12) & 3, m = (i >> 14) & 1, l = i >> 15;
    int k = cc * 32 + q * 8 + j, n = t * 16 + ii;
    const float* W = m ? Wr : Wl;
    float w = W[l * HID * HID + k * HID + n];
    unsigned short hi = f2bf(w);
    unsigned short lo = f2bf(w - bf2f(hi));
    wswh[i] = hi;
    wswl[i] = lo;
  }
  if (i < 2048) {  // zero 64 pad rows of each h buffer (rows NN..NN+63)
    int b = i >> 10, r = (i >> 4) & 63, u = i & 15;
    unsigned short* pad = (b ? hB : hA) + (size_t)(NN + r) * HID;
    *(uint4*)&pad[u * 8] = make_uint4(0u, 0u, 0u, 0u);
  }
}

// ---- exclusive scan (3 kernels) ----
__global__ void k_scan1(const int* __restrict__ deg, int* __restrict__ offs,
                        int* __restrict__ bsum) {
  int i = blockIdx.x * 256 + threadIdx.x;
  int v = (i < NN) ? deg[i] : 0;
  int lane = threadIdx.x & 63, wv = threadIdx.x >> 6;
  int x = v;
  #pragma unroll
  for (int d = 1; d < 64; d <<= 1) {
    int y = __shfl_up(x, d, 64);
    if (lane >= d) x += y;
  }
  __shared__ int wsum[4];
  if (lane == 63) wsum[wv] = x;
  __syncthreads();
  if (threadIdx.x == 0) {
    int s = 0;
    for (int k = 0; k < 4; k++) { int t = wsum[k]; wsum[k] = s; s += t; }
    bsum[blockIdx.x] = s;
  }
  __syncthreads();
  if (i < NN) offs[i] = x - v + wsum[wv];
}

__global__ void k_scan2(int* __restrict__ bsum, int nb) {
  int i = threadIdx.x;
  int v = (i < nb) ? bsum[i] : 0;
  int lane = threadIdx.x & 63, wv = threadIdx.x >> 6;
  int x = v;
  #pragma unroll
  for (int d = 1; d < 64; d <<= 1) {
    int y = __shfl_up(x, d, 64);
    if (lane >= d) x += y;
  }
  __shared__ int wsum[4];
  if (lane == 63) wsum[wv] = x;
  __syncthreads();
  if (threadIdx.x == 0) {
    int s = 0;
    for (int k = 0; k < 4; k++) { int t = wsum[k]; wsum[k] = s; s += t; }
  }
  __syncthreads();
  if (i < nb) bsum[i] = x - v + wsum[wv];
}

__global__ void k_scan3(const int* __restrict__ deg, int* __restrict__ offs,
                        const int* __restrict__ bsum, float* __restrict__ invd) {
  int i = blockIdx.x * 256 + threadIdx.x;
  if (i < NN) {
    offs[i] += bsum[blockIdx.x];
    int d = deg[i];
    invd[i] = 1.0f / (float)(d > 0 ? d : 1);
    if (i == 0) offs[NN] = NE;
  }
}

// ---- CSR fill: dst-range partitioned, XCD-affine (blockIdx%8 -> XCD round robin).
#define FILL_CHUNK (NE / 128)   // 6250
__global__ void k_fill(const int* __restrict__ src, const int* __restrict__ dst,
                       const int* __restrict__ offs, int* __restrict__ cur,
                       int* __restrict__ csr) {
  const int r = blockIdx.x & 7;          // intended XCD
  const int chunk = blockIdx.x >> 3;     // 0..127
  const int lo = r * (NN / 8), hi = lo + (NN / 8);
  const int e0 = chunk * FILL_CHUNK;
  for (int e = e0 + threadIdx.x; e < e0 + FILL_CHUNK; e += 256) {
    int d = dst[e];
    if (d >= lo && d < hi) {
      int p = atomicAdd(&cur[d], 1);
      csr[offs[d] + p] = src[e];
    }
  }
}

// ---- degree-bucket sort (LDS-privatized; r12 lesson: 50000 value-returning
// global atomics on one 64B line = 377us. Now: LDS histogram per block, ONE
// global atomic per bucket per block = 3136 total).
__global__ void k_b1(const int* __restrict__ deg, int* __restrict__ bcnt) {
  __shared__ int l[16];
  if (threadIdx.x < 16) l[threadIdx.x] = 0;
  __syncthreads();
  int i = blockIdx.x * 256 + threadIdx.x;
  if (i < NN) {
    int b = (deg[i] + 7) >> 3; if (b > 15) b = 15;
    atomicAdd(&l[b], 1);
  }
  __syncthreads();
  if (threadIdx.x < 16 && l[threadIdx.x]) atomicAdd(&bcnt[threadIdx.x], l[threadIdx.x]);
}
__global__ void k_bscan(const int* __restrict__ bcnt, int* __restrict__ boff) {
  if (threadIdx.x == 0) {
    int s = 0;
    for (int k = 0; k < 16; k++) { boff[k] = s; s += bcnt[k]; }
  }
}
__global__ void k_b2(const int* __restrict__ deg, int* __restrict__ boff,
                     int* __restrict__ perm) {
  __shared__ int lcnt[16], lbase[16];
  if (threadIdx.x < 16) lcnt[threadIdx.x] = 0;
  __syncthreads();
  int i = blockIdx.x * 256 + threadIdx.x;
  int b = 0, r = 0;
  if (i < NN) {
    b = (deg[i] + 7) >> 3; if (b > 15) b = 15;
    r = atomicAdd(&lcnt[b], 1);
  }
  __syncthreads();
  if (threadIdx.x < 16)
    lbase[threadIdx.x] = lcnt[threadIdx.x] ? atomicAdd(&boff[threadIdx.x], lcnt[threadIdx.x]) : 0;
  __syncthreads();
  if (i < NN) perm[lbase[b] + r] = i;
}

#define ACC8(V) { a0 += bflo(V.x); a1 += bfhi(V.x); a2 += bflo(V.y); \
                  a3 += bfhi(V.y); a4 += bflo(V.z); a5 += bfhi(V.z); \
                  a6 += bflo(V.w); a7 += bfhi(V.w); }

#define LOADSTRIP(P0,P1,P2,P3,P4,P5,P6,P7,IDX) \
  P0 = *(const uint4*)(rowbase + (size_t)__shfl(IDX, 0, 8) * HID); \
  P1 = *(const uint4*)(rowbase + (size_t)__shfl(IDX, 1, 8) * HID); \
  P2 = *(const uint4*)(rowbase + (size_t)__shfl(IDX, 2, 8) * HID); \
  P3 = *(const uint4*)(rowbase + (size_t)__shfl(IDX, 3, 8) * HID); \
  P4 = *(const uint4*)(rowbase + (size_t)__shfl(IDX, 4, 8) * HID); \
  P5 = *(const uint4*)(rowbase + (size_t)__shfl(IDX, 5, 8) * HID); \
  P6 = *(const uint4*)(rowbase + (size_t)__shfl(IDX, 6, 8) * HID); \
  P7 = *(const uint4*)(rowbase + (size_t)__shfl(IDX, 7, 8) * HID);

// ---- gather: pipelined strip (r11, proven) + degree-sorted node order via
// perm[] (wave's 8 nodes = same bucket = equal trip counts).
__global__ __launch_bounds__(256, 6) void k_agg(const unsigned short* __restrict__ curh,
                                                const int* __restrict__ offs,
                                                const int* __restrict__ csr,
                                                const float* __restrict__ invd,
                                                const int* __restrict__ perm,
                                                unsigned short* __restrict__ agg) {
  const int slice = blockIdx.x & 1;    // column band
  const int tid = threadIdx.x;
  const int grp = tid >> 3, l = tid & 7;
  const int pos = (blockIdx.x >> 1) * 32 + grp;
  if (pos >= NN) return;
  const int node = perm[pos];
  const unsigned short* rowbase = curh + slice * 64 + l * 8;
  float a0 = 0.f, a1 = 0.f, a2 = 0.f, a3 = 0.f;
  float a4 = 0.f, a5 = 0.f, a6 = 0.f, a7 = 0.f;
  const int s = offs[node], e = offs[node + 1];
  if (s < e) {
    uint4 p0, p1, p2, p3, p4, p5, p6, p7;
    int idx = (s + l < e) ? csr[s + l] : NN;   // pad row NN = zeros
    LOADSTRIP(p0, p1, p2, p3, p4, p5, p6, p7, idx)
    for (int base = s + 8; base < e; base += 8) {
      uint4 n0, n1, n2, n3, n4, n5, n6, n7;
      int idx2 = (base + l < e) ? csr[base + l] : NN;
      LOADSTRIP(n0, n1, n2, n3, n4, n5, n6, n7, idx2)   // in flight during ACC
      ACC8(p0) ACC8(p1) ACC8(p2) ACC8(p3)
      ACC8(p4) ACC8(p5) ACC8(p6) ACC8(p7)
      p0 = n0; p1 = n1; p2 = n2; p3 = n3;
      p4 = n4; p5 = n5; p6 = n6; p7 = n7;
    }
    ACC8(p0) ACC8(p1) ACC8(p2) ACC8(p3)
    ACC8(p4) ACC8(p5) ACC8(p6) ACC8(p7)
  }
  float sc = invd[node];
  a0 *= sc; a1 *= sc; a2 *= sc; a3 *= sc;
  a4 *= sc; a5 *= sc; a6 *= sc; a7 *= sc;
  unsigned int w0 = (unsigned int)f2bf(a0) | ((unsigned int)f2bf(a1) << 16);
  unsigned int w1 = (unsigned int)f2bf(a2) | ((unsigned int)f2bf(a3) << 16);
  unsigned int w2 = (unsigned int)f2bf(a4) | ((unsigned int)f2bf(a5) << 16);
  unsigned int w3 = (unsigned int)f2bf(a6) | ((unsigned int)f2bf(a7) << 16);
  *(uint4*)(agg + (size_t)node * HID + slice * 64 + l * 8) =
      make_uint4(w0, w1, w2, w3);
}

// ---- GEMM: round-11 single-buffered version (proven in the 486 config;
// dbuf variant shelved until degree-sort's sign is isolated) ----
__global__ __launch_bounds__(256) void k_gemm(const unsigned short* __restrict__ agg,
                                              const unsigned short* __restrict__ curh,
                                              const unsigned short* __restrict__ wswh,
                                              const unsigned short* __restrict__ wswl,
                                              const float* __restrict__ bias,
                                              unsigned short* __restrict__ out,
                                              int relu) {
  __shared__ __align__(16) unsigned short sW2[8192];  // Whi | Wlo for one chunk
  const int tid = threadIdx.x;
  const int lane = tid & 63, wv = tid >> 6;
  const int row0 = blockIdx.x * 64;
  const int mr = (wv << 4) + (lane & 15);
  const int q = lane >> 4;
  const unsigned short* aRow = agg + (size_t)(row0 + mr) * HID + q * 8;
  const unsigned short* hRow = curh + (size_t)(row0 + mr) * HID + q * 8;

  f32x4 acc[8];
  #pragma unroll
  for (int t = 0; t < 8; t++) acc[t] = (f32x4){0.f, 0.f, 0.f, 0.f};

  for (int c = 0; c < 8; ++c) {
    const uint4* wh = (const uint4*)(wswh + c * 4096);
    const uint4* wl = (const uint4*)(wswl + c * 4096);
    ((uint4*)sW2)[tid] = wh[tid];
    ((uint4*)sW2)[tid + 256] = wh[tid + 256];
    ((uint4*)sW2)[tid + 512] = wl[tid];
    ((uint4*)sW2)[tid + 768] = wl[tid + 256];
    __syncthreads();
    bf16x8 a = *(const bf16x8*)(((c < 4) ? aRow : hRow) + (c & 3) * 32);
    #pragma unroll
    for (int t = 0; t < 8; t++) {
      bf16x8 bh = *(const bf16x8*)&sW2[(t * 4 + q) * 128 + (lane & 15) * 8];
      bf16x8 bl2 = *(const bf16x8*)&sW2[4096 + (t * 4 + q) * 128 + (lane & 15) * 8];
      acc[t] = __builtin_amdgcn_mfma_f32_16x16x32_bf16(a, bh, acc[t], 0, 0, 0);
      acc[t] = __builtin_amdgcn_mfma_f32_16x16x32_bf16(a, bl2, acc[t], 0, 0, 0);
    }
    __syncthreads();
  }

  const int ci = lane & 15;
  const int rb = (wv << 4) + (lane >> 4) * 4;
  #pragma unroll
  for (int t = 0; t < 8; t++) {
    int n = t * 16 + ci;
    float bn = bias[n];
    #pragma unroll
    for (int r2 = 0; r2 < 4; r2++) {
      int row = row0 + rb + r2;
      if (row < NN) {
        float v = acc[t][r2] + bn;
        if (relu) v = fmaxf(v, 0.f);
        out[(size_t)row * HID + n] = f2bf(v);
      }
    }
  }
}

// ---- global add pool (batch sorted -> binary search; 2-row MLP) ----
__global__ void k_pool(const unsigned short* __restrict__ h,
                       const int* __restrict__ batch, float* __restrict__ pooled) {
  int g = blockIdx.x;
  __shared__ int rng[2];
  __shared__ float tmp[HID];
  if (threadIdx.x < 2) {
    int target = g + threadIdx.x;
    int lo = 0, hi = NN;
    while (lo < hi) {
      int mid = (lo + hi) >> 1;
      if (batch[mid] < target) lo = mid + 1; else hi = mid;
    }
    rng[threadIdx.x] = lo;
  }
  __syncthreads();
  int s = rng[0], e = rng[1];
  int f = threadIdx.x & 127, ro = threadIdx.x >> 7;  // 256 threads: 2 row streams
  float a = 0.f;
  for (int r = s + ro; r < e; r += 2) a += bf2f(h[(size_t)r * HID + f]);
  if (ro == 1) tmp[f] = a;
  __syncthreads();
  if (ro == 0) pooled[g * HID + f] = a + tmp[f];
}

// ---- final projection 128 -> 2 (all fp32) ----
__global__ void k_out(const float* __restrict__ pooled,
                      const float* __restrict__ Wout,
                      const float* __restrict__ bout,
                      float* __restrict__ out) {
  int g = blockIdx.x;
  int l = threadIdx.x;  // 64
  float a = pooled[g * HID + l], b = pooled[g * HID + 64 + l];
  float p0 = a * Wout[l * 2] + b * Wout[(l + 64) * 2];
  float p1 = a * Wout[l * 2 + 1] + b * Wout[(l + 64) * 2 + 1];
  #pragma unroll
  for (int d = 32; d; d >>= 1) {
    p0 += __shfl_down(p0, d, 64);
    p1 += __shfl_down(p1, d, 64);
  }
  if (l == 0) {
    out[g * 2] = p0 + bout[0];
    out[g * 2 + 1] = p1 + bout[1];
  }
}

extern "C" void kernel_launch(void* const* d_in, const int* in_sizes, int n_in,
                              void* d_out, int out_size, void* d_ws, size_t ws_size,
                              hipStream_t stream) {
  const float* x = (const float*)d_in[0];
  const int* ei = (const int*)d_in[1];
  const int* batch = (const int*)d_in[2];
  const float* Wl = (const float*)d_in[3];
  const float* Wr = (const float*)d_in[4];
  const float* bl = (const float*)d_in[5];
  const float* Wout = (const float*)d_in[6];
  const float* bout = (const float*)d_in[7];
  float* out = (float*)d_out;
  const int* srcE = ei;
  const int* dstE = ei + NE;

  // workspace layout (~43 MB); h buffers padded to NN+64 rows (zeroed)
  char* w = (char*)d_ws;
  unsigned short* hA = (unsigned short*)w;  w += (size_t)(NN + 64) * HID * 2;
  unsigned short* hB = (unsigned short*)w;  w += (size_t)(NN + 64) * HID * 2;
  unsigned short* agg = (unsigned short*)w; w += (size_t)(NN + 64) * HID * 2;
  float* invd = (float*)w;   w += (size_t)NN * 4;
  float* pooled = (float*)w; w += (size_t)NG * HID * 4;
  int* deg = (int*)w;  w += (size_t)NN * 4;
  int* cur = (int*)w;  w += (size_t)NN * 4;      // adjacent to deg
  int* bcnt = (int*)w; w += 16 * 4;              // adjacent: covered by memset
  int* boff = (int*)w; w += 16 * 4;
  int* perm = (int*)w; w += (size_t)NN * 4;
  int* offs = (int*)w; w += (size_t)50004 * 4;
  int* csr = (int*)w;  w += (size_t)NE * 4;
  int* bsum = (int*)w; w += 256 * 4;
  unsigned short* wswh = (unsigned short*)w; w += (size_t)NL * 2 * 4 * 4096 * 2;
  unsigned short* wswl = (unsigned short*)w;

  hipMemsetAsync(deg, 0, ((size_t)NN * 2 + 16) * 4, stream);  // deg+cur+bcnt
  k_pre<<<(NN * HID / 4 + 255) / 256, 256, 0, stream>>>(x, hA, hB, dstE, deg,
                                                        Wl, Wr, wswh, wswl);
  int nb = (NN + 255) / 256;
  k_scan1<<<nb, 256, 0, stream>>>(deg, offs, bsum);
  k_scan2<<<1, 256, 0, stream>>>(bsum, nb);
  k_scan3<<<nb, 256, 0, stream>>>(deg, offs, bsum, invd);
  k_fill<<<1024, 256, 0, stream>>>(srcE, dstE, offs, cur, csr);
  k_b1<<<nb, 256, 0, stream>>>(deg, bcnt);
  k_bscan<<<1, 64, 0, stream>>>(bcnt, boff);
  k_b2<<<nb, 256, 0, stream>>>(deg, boff, perm);

  unsigned short* curh = hA;
  unsigned short* nxth = hB;
  const int aggGrid = ((NN + 31) / 32) * 2;  // 1563*2 = 3126
  for (int l = 0; l < NL; l++) {
    k_agg<<<aggGrid, 256, 0, stream>>>(curh, offs, csr, invd, perm, agg);
    k_gemm<<<(NN + 63) / 64, 256, 0, stream>>>(agg, curh,
                                               wswh + (size_t)l * 2 * 4 * 4096,
                                               wswl + (size_t)l * 2 * 4 * 4096,
                                               bl + l * HID, nxth,
                                               (l < NL - 1) ? 1 : 0);
    unsigned short* t = curh; curh = nxth; nxth = t;
  }
  k_pool<<<NG, 256, 0, stream>>>(curh, batch, pooled);
  k_out<<<NG, 64, 0, stream>>>(pooled, Wout, bout, out);
}

// Round 14
// 439.292 us; speedup vs baseline: 2.8222x; 1.1635x over previous
//
#include <hip/hip_runtime.h>
#include <stdint.h>

#define NN 50000
#define NE 800000
#define HID 128
#define NG 500
#define NL 7

typedef short bf16x8 __attribute__((ext_vector_type(8)));
typedef float f32x4 __attribute__((ext_vector_type(4)));

__device__ __forceinline__ unsigned short f2bf(float f) {
  unsigned int u = __builtin_bit_cast(unsigned int, f);
  u += 0x7FFFu + ((u >> 16) & 1u);
  return (unsigned short)(u >> 16);
}
__device__ __forceinline__ float bf2f(unsigned short h) {
  unsigned int u = ((unsigned int)h) << 16;
  return __builtin_bit_cast(float, u);
}
__device__ __forceinline__ float bflo(unsigned int u) {
  return __builtin_bit_cast(float, u << 16);
}
__device__ __forceinline__ float bfhi(unsigned int u) {
  return __builtin_bit_cast(float, u & 0xffff0000u);
}

// ---- fused preprocessing: cvt + pad rows + degree histogram (rank-capturing)
// + weight swizzle. rank[e] = this edge's arrival order at its dst -> k_fill
// needs no atomics (r13 lesson: cur[] atomics made k_fill 44us).
__global__ void k_pre(const float* __restrict__ x, unsigned short* __restrict__ hA,
                      unsigned short* __restrict__ hB,
                      const int* __restrict__ dstE, int* __restrict__ deg,
                      int* __restrict__ rank,
                      const float* __restrict__ Wl, const float* __restrict__ Wr,
                      unsigned short* __restrict__ wswh,
                      unsigned short* __restrict__ wswl) {
  int i = blockIdx.x * 256 + threadIdx.x;
  if (i < NN * HID / 4) {
    float4 v = ((const float4*)x)[i];
    ushort4 r;
    r.x = f2bf(v.x); r.y = f2bf(v.y); r.z = f2bf(v.z); r.w = f2bf(v.w);
    ((ushort4*)hA)[i] = r;
  }
  if (i < NE) rank[i] = atomicAdd(&deg[dstE[i]], 1);
  if (i < NL * 2 * 4 * 4096) {
    int j = i & 7, ii = (i >> 3) & 15, q = (i >> 7) & 3, t = (i >> 9) & 7;
    int cc = (i >> 12) & 3, m = (i >> 14) & 1, l = i >> 15;
    int k = cc * 32 + q * 8 + j, n = t * 16 + ii;
    const float* W = m ? Wr : Wl;
    float w = W[l * HID * HID + k * HID + n];
    unsigned short hi = f2bf(w);
    unsigned short lo = f2bf(w - bf2f(hi));
    wswh[i] = hi;
    wswl[i] = lo;
  }
  if (i < 2048) {  // zero 64 pad rows of each h buffer (rows NN..NN+63)
    int b = i >> 10, r = (i >> 4) & 63, u = i & 15;
    unsigned short* pad = (b ? hB : hA) + (size_t)(NN + r) * HID;
    *(uint4*)&pad[u * 8] = make_uint4(0u, 0u, 0u, 0u);
  }
}

// ---- exclusive scan (3 kernels) ----
__global__ void k_scan1(const int* __restrict__ deg, int* __restrict__ offs,
                        int* __restrict__ bsum) {
  int i = blockIdx.x * 256 + threadIdx.x;
  int v = (i < NN) ? deg[i] : 0;
  int lane = threadIdx.x & 63, wv = threadIdx.x >> 6;
  int x = v;
  #pragma unroll
  for (int d = 1; d < 64; d <<= 1) {
    int y = __shfl_up(x, d, 64);
    if (lane >= d) x += y;
  }
  __shared__ int wsum[4];
  if (lane == 63) wsum[wv] = x;
  __syncthreads();
  if (threadIdx.x == 0) {
    int s = 0;
    for (int k = 0; k < 4; k++) { int t = wsum[k]; wsum[k] = s; s += t; }
    bsum[blockIdx.x] = s;
  }
  __syncthreads();
  if (i < NN) offs[i] = x - v + wsum[wv];
}

__global__ void k_scan2(int* __restrict__ bsum, int nb) {
  int i = threadIdx.x;
  int v = (i < nb) ? bsum[i] : 0;
  int lane = threadIdx.x & 63, wv = threadIdx.x >> 6;
  int x = v;
  #pragma unroll
  for (int d = 1; d < 64; d <<= 1) {
    int y = __shfl_up(x, d, 64);
    if (lane >= d) x += y;
  }
  __shared__ int wsum[4];
  if (lane == 63) wsum[wv] = x;
  __syncthreads();
  if (threadIdx.x == 0) {
    int s = 0;
    for (int k = 0; k < 4; k++) { int t = wsum[k]; wsum[k] = s; s += t; }
  }
  __syncthreads();
  if (i < nb) bsum[i] = x - v + wsum[wv];
}

__global__ void k_scan3(const int* __restrict__ deg, int* __restrict__ offs,
                        const int* __restrict__ bsum, float* __restrict__ invd) {
  int i = blockIdx.x * 256 + threadIdx.x;
  if (i < NN) {
    offs[i] += bsum[blockIdx.x];
    int d = deg[i];
    invd[i] = 1.0f / (float)(d > 0 ? d : 1);
    if (i == 0) offs[NN] = NE;
  }
}

// ---- CSR fill: atomic-free (rank precomputed in k_pre); dst-range
// partitioned for XCD write locality (blockIdx%8 -> XCD round robin).
#define FILL_CHUNK (NE / 128)   // 6250
__global__ void k_fill(const int* __restrict__ src, const int* __restrict__ dst,
                       const int* __restrict__ rank, const int* __restrict__ offs,
                       int* __restrict__ csr) {
  const int r = blockIdx.x & 7;          // intended XCD
  const int chunk = blockIdx.x >> 3;     // 0..127
  const int lo = r * (NN / 8), hi = lo + (NN / 8);
  const int e0 = chunk * FILL_CHUNK;
  for (int e = e0 + threadIdx.x; e < e0 + FILL_CHUNK; e += 256) {
    int d = dst[e];
    if (d >= lo && d < hi) csr[offs[d] + rank[e]] = src[e];
  }
}

#define ACC8(V) { a0 += bflo(V.x); a1 += bfhi(V.x); a2 += bflo(V.y); \
                  a3 += bfhi(V.y); a4 += bflo(V.z); a5 += bfhi(V.z); \
                  a6 += bflo(V.w); a7 += bfhi(V.w); }

#define LOADSTRIP(P0,P1,P2,P3,P4,P5,P6,P7,IDX) \
  P0 = *(const uint4*)(rowbase + (size_t)__shfl(IDX, 0, 8) * HID); \
  P1 = *(const uint4*)(rowbase + (size_t)__shfl(IDX, 1, 8) * HID); \
  P2 = *(const uint4*)(rowbase + (size_t)__shfl(IDX, 2, 8) * HID); \
  P3 = *(const uint4*)(rowbase + (size_t)__shfl(IDX, 3, 8) * HID); \
  P4 = *(const uint4*)(rowbase + (size_t)__shfl(IDX, 4, 8) * HID); \
  P5 = *(const uint4*)(rowbase + (size_t)__shfl(IDX, 5, 8) * HID); \
  P6 = *(const uint4*)(rowbase + (size_t)__shfl(IDX, 6, 8) * HID); \
  P7 = *(const uint4*)(rowbase + (size_t)__shfl(IDX, 7, 8) * HID);

// ---- gather: exact round-11 config (486-holder): 8-lane groups, 16B/lane,
// software-pipelined strip, half-band + quarter-node %8 XCD mapping, natural
// node order (r13: degree-sorted perm = -25us regression, reverted).
__global__ __launch_bounds__(256, 6) void k_agg(const unsigned short* __restrict__ curh,
                                                const int* __restrict__ offs,
                                                const int* __restrict__ csr,
                                                const float* __restrict__ invd,
                                                unsigned short* __restrict__ agg) {
  const int g = blockIdx.x & 7;        // XCD id
  const int slice = g & 1;             // column band
  const int q = g >> 1;                // node quarter 0..3
  const int tid = threadIdx.x;
  const int grp = tid >> 3, l = tid & 7;
  const int local = (blockIdx.x >> 3) * 32 + grp;
  if (local >= NN / 4) return;
  const int node = q * (NN / 4) + local;
  const unsigned short* rowbase = curh + slice * 64 + l * 8;
  float a0 = 0.f, a1 = 0.f, a2 = 0.f, a3 = 0.f;
  float a4 = 0.f, a5 = 0.f, a6 = 0.f, a7 = 0.f;
  const int s = offs[node], e = offs[node + 1];
  if (s < e) {
    uint4 p0, p1, p2, p3, p4, p5, p6, p7;
    int idx = (s + l < e) ? csr[s + l] : NN;   // pad row NN = zeros
    LOADSTRIP(p0, p1, p2, p3, p4, p5, p6, p7, idx)
    for (int base = s + 8; base < e; base += 8) {
      uint4 n0, n1, n2, n3, n4, n5, n6, n7;
      int idx2 = (base + l < e) ? csr[base + l] : NN;
      LOADSTRIP(n0, n1, n2, n3, n4, n5, n6, n7, idx2)   // in flight during ACC
      ACC8(p0) ACC8(p1) ACC8(p2) ACC8(p3)
      ACC8(p4) ACC8(p5) ACC8(p6) ACC8(p7)
      p0 = n0; p1 = n1; p2 = n2; p3 = n3;
      p4 = n4; p5 = n5; p6 = n6; p7 = n7;
    }
    ACC8(p0) ACC8(p1) ACC8(p2) ACC8(p3)
    ACC8(p4) ACC8(p5) ACC8(p6) ACC8(p7)
  }
  float sc = invd[node];
  a0 *= sc; a1 *= sc; a2 *= sc; a3 *= sc;
  a4 *= sc; a5 *= sc; a6 *= sc; a7 *= sc;
  unsigned int w0 = (unsigned int)f2bf(a0) | ((unsigned int)f2bf(a1) << 16);
  unsigned int w1 = (unsigned int)f2bf(a2) | ((unsigned int)f2bf(a3) << 16);
  unsigned int w2 = (unsigned int)f2bf(a4) | ((unsigned int)f2bf(a5) << 16);
  unsigned int w3 = (unsigned int)f2bf(a6) | ((unsigned int)f2bf(a7) << 16);
  *(uint4*)(agg + (size_t)node * HID + slice * 64 + l * 8) =
      make_uint4(w0, w1, w2, w3);
}

// ---- GEMM: double-buffered weight staging (r12/r13 arithmetic: dbuf = -26us
// vs single-buf). Chunk c+1's global loads issue before chunk c's MFMAs, land
// in the other LDS buffer after; 1 barrier/iter (9 vs 16).
__global__ __launch_bounds__(256) void k_gemm(const unsigned short* __restrict__ agg,
                                              const unsigned short* __restrict__ curh,
                                              const unsigned short* __restrict__ wswh,
                                              const unsigned short* __restrict__ wswl,
                                              const float* __restrict__ bias,
                                              unsigned short* __restrict__ out,
                                              int relu) {
  __shared__ __align__(16) unsigned short sW2[2][8192];  // double-buffered Whi|Wlo
  const int tid = threadIdx.x;
  const int lane = tid & 63, wv = tid >> 6;
  const int row0 = blockIdx.x * 64;
  const int mr = (wv << 4) + (lane & 15);
  const int q = lane >> 4;
  const unsigned short* aRow = agg + (size_t)(row0 + mr) * HID + q * 8;
  const unsigned short* hRow = curh + (size_t)(row0 + mr) * HID + q * 8;

  f32x4 acc[8];
  #pragma unroll
  for (int t = 0; t < 8; t++) acc[t] = (f32x4){0.f, 0.f, 0.f, 0.f};

  {
    const uint4* wh = (const uint4*)wswh;
    const uint4* wl = (const uint4*)wswl;
    ((uint4*)sW2[0])[tid] = wh[tid];
    ((uint4*)sW2[0])[tid + 256] = wh[tid + 256];
    ((uint4*)sW2[0])[tid + 512] = wl[tid];
    ((uint4*)sW2[0])[tid + 768] = wl[tid + 256];
  }
  __syncthreads();

  for (int c = 0; c < 8; ++c) {
    uint4 u0, u1, u2, u3;
    if (c < 7) {
      const uint4* wh = (const uint4*)(wswh + (c + 1) * 4096);
      const uint4* wl = (const uint4*)(wswl + (c + 1) * 4096);
      u0 = wh[tid]; u1 = wh[tid + 256]; u2 = wl[tid]; u3 = wl[tid + 256];
    }
    const unsigned short* buf = sW2[c & 1];
    bf16x8 a = *(const bf16x8*)(((c < 4) ? aRow : hRow) + (c & 3) * 32);
    #pragma unroll
    for (int t = 0; t < 8; t++) {
      bf16x8 bh = *(const bf16x8*)&buf[(t * 4 + q) * 128 + (lane & 15) * 8];
      bf16x8 bl2 = *(const bf16x8*)&buf[4096 + (t * 4 + q) * 128 + (lane & 15) * 8];
      acc[t] = __builtin_amdgcn_mfma_f32_16x16x32_bf16(a, bh, acc[t], 0, 0, 0);
      acc[t] = __builtin_amdgcn_mfma_f32_16x16x32_bf16(a, bl2, acc[t], 0, 0, 0);
    }
    if (c < 7) {
      unsigned short* nb = sW2[(c + 1) & 1];
      ((uint4*)nb)[tid] = u0;
      ((uint4*)nb)[tid + 256] = u1;
      ((uint4*)nb)[tid + 512] = u2;
      ((uint4*)nb)[tid + 768] = u3;
    }
    __syncthreads();
  }

  const int ci = lane & 15;
  const int rb = (wv << 4) + (lane >> 4) * 4;
  #pragma unroll
  for (int t = 0; t < 8; t++) {
    int n = t * 16 + ci;
    float bn = bias[n];
    #pragma unroll
    for (int r2 = 0; r2 < 4; r2++) {
      int row = row0 + rb + r2;
      if (row < NN) {
        float v = acc[t][r2] + bn;
        if (relu) v = fmaxf(v, 0.f);
        out[(size_t)row * HID + n] = f2bf(v);
      }
    }
  }
}

// ---- global add pool (batch sorted -> binary search; 2-row MLP) ----
__global__ void k_pool(const unsigned short* __restrict__ h,
                       const int* __restrict__ batch, float* __restrict__ pooled) {
  int g = blockIdx.x;
  __shared__ int rng[2];
  __shared__ float tmp[HID];
  if (threadIdx.x < 2) {
    int target = g + threadIdx.x;
    int lo = 0, hi = NN;
    while (lo < hi) {
      int mid = (lo + hi) >> 1;
      if (batch[mid] < target) lo = mid + 1; else hi = mid;
    }
    rng[threadIdx.x] = lo;
  }
  __syncthreads();
  int s = rng[0], e = rng[1];
  int f = threadIdx.x & 127, ro = threadIdx.x >> 7;  // 256 threads: 2 row streams
  float a = 0.f;
  for (int r = s + ro; r < e; r += 2) a += bf2f(h[(size_t)r * HID + f]);
  if (ro == 1) tmp[f] = a;
  __syncthreads();
  if (ro == 0) pooled[g * HID + f] = a + tmp[f];
}

// ---- final projection 128 -> 2 (all fp32) ----
__global__ void k_out(const float* __restrict__ pooled,
                      const float* __restrict__ Wout,
                      const float* __restrict__ bout,
                      float* __restrict__ out) {
  int g = blockIdx.x;
  int l = threadIdx.x;  // 64
  float a = pooled[g * HID + l], b = pooled[g * HID + 64 + l];
  float p0 = a * Wout[l * 2] + b * Wout[(l + 64) * 2];
  float p1 = a * Wout[l * 2 + 1] + b * Wout[(l + 64) * 2 + 1];
  #pragma unroll
  for (int d = 32; d; d >>= 1) {
    p0 += __shfl_down(p0, d, 64);
    p1 += __shfl_down(p1, d, 64);
  }
  if (l == 0) {
    out[g * 2] = p0 + bout[0];
    out[g * 2 + 1] = p1 + bout[1];
  }
}

extern "C" void kernel_launch(void* const* d_in, const int* in_sizes, int n_in,
                              void* d_out, int out_size, void* d_ws, size_t ws_size,
                              hipStream_t stream) {
  const float* x = (const float*)d_in[0];
  const int* ei = (const int*)d_in[1];
  const int* batch = (const int*)d_in[2];
  const float* Wl = (const float*)d_in[3];
  const float* Wr = (const float*)d_in[4];
  const float* bl = (const float*)d_in[5];
  const float* Wout = (const float*)d_in[6];
  const float* bout = (const float*)d_in[7];
  float* out = (float*)d_out;
  const int* srcE = ei;
  const int* dstE = ei + NE;

  // workspace layout (~46 MB); h buffers padded to NN+64 rows (zeroed)
  char* w = (char*)d_ws;
  unsigned short* hA = (unsigned short*)w;  w += (size_t)(NN + 64) * HID * 2;
  unsigned short* hB = (unsigned short*)w;  w += (size_t)(NN + 64) * HID * 2;
  unsigned short* agg = (unsigned short*)w; w += (size_t)(NN + 64) * HID * 2;
  float* invd = (float*)w;   w += (size_t)NN * 4;
  float* pooled = (float*)w; w += (size_t)NG * HID * 4;
  int* deg = (int*)w;  w += (size_t)NN * 4;
  int* rank = (int*)w; w += (size_t)NE * 4;
  int* offs = (int*)w; w += (size_t)50004 * 4;
  int* csr = (int*)w;  w += (size_t)NE * 4;
  int* bsum = (int*)w; w += 256 * 4;
  unsigned short* wswh = (unsigned short*)w; w += (size_t)NL * 2 * 4 * 4096 * 2;
  unsigned short* wswl = (unsigned short*)w;

  hipMemsetAsync(deg, 0, (size_t)NN * 4, stream);
  k_pre<<<(NN * HID / 4 + 255) / 256, 256, 0, stream>>>(x, hA, hB, dstE, deg,
                                                        rank, Wl, Wr, wswh, wswl);
  int nb = (NN + 255) / 256;
  k_scan1<<<nb, 256, 0, stream>>>(deg, offs, bsum);
  k_scan2<<<1, 256, 0, stream>>>(bsum, nb);
  k_scan3<<<nb, 256, 0, stream>>>(deg, offs, bsum, invd);
  k_fill<<<1024, 256, 0, stream>>>(srcE, dstE, rank, offs, csr);

  unsigned short* curh = hA;
  unsigned short* nxth = hB;
  const int aggGrid = ((NN / 4 + 31) / 32) * 8;  // 391*8 = 3128
  for (int l = 0; l < NL; l++) {
    k_agg<<<aggGrid, 256, 0, stream>>>(curh, offs, csr, invd, agg);
    k_gemm<<<(NN + 63) / 64, 256, 0, stream>>>(agg, curh,
                                               wswh + (size_t)l * 2 * 4 * 4096,
                                               wswl + (size_t)l * 2 * 4 * 4096,
                                               bl + l * HID, nxth,
                                               (l < NL - 1) ? 1 : 0);
    unsigned short* t = curh; curh = nxth; nxth = t;
  }
  k_pool<<<NG, 256, 0, stream>>>(curh, batch, pooled);
  k_out<<<NG, 64, 0, stream>>>(pooled, Wout, bout, out);
}